// Round 3
// baseline (43.713 us; speedup 1.0000x reference)
//
#include <hip/hip_runtime.h>
#include <float.h>

#define NPTS  4096
#define NB    8
#define BLOCK 256
#define QPT   16          // queries per thread (16*256 = 4096 per (b,dir))

typedef float v2f __attribute__((ext_vector_type(2)));

__device__ __forceinline__ v2f pk_fma(v2f a, v2f b, v2f c) {
    v2f d;
    asm("v_pk_fma_f32 %0, %1, %2, %3" : "=v"(d) : "v"(a), "v"(b), "v"(c));
    return d;
}

// ---------------- main: per-slice partial mins (packed point pairs) ----------
// grid (S, 16), block 256.  bdir = b*2+dir. dir0: q=preds db=gts; dir1 swapped.
__global__ void __launch_bounds__(BLOCK) chamfer_main(
    const float* __restrict__ preds,
    const float* __restrict__ gts,
    float* __restrict__ part, int S)
{
    // per point-pair: float4{x0,x1,y0,y1}, float4{z0,z1,h0,h1}; up to 256 pairs
    __shared__ float4 pt[256 * 2];        // 8 KB

    const int slice = blockIdx.x, bdir = blockIdx.y;
    const int b = bdir >> 1, dir = bdir & 1;
    const int tid = threadIdx.x;
    const int pts_slice = NPTS / S;
    const int pairs = pts_slice >> 1;

    const float* query = ((dir == 0) ? preds : gts) + (size_t)b * NPTS * 3;
    const float* db    = ((dir == 0) ? gts   : preds) + (size_t)b * NPTS * 3;

    // stage db pairs into LDS, packed SoA-by-2 with ||p||^2
    for (int i = tid; i < pairs; i += BLOCK) {
        const float* p = db + (size_t)(slice * pts_slice + 2 * i) * 3;
        float2 u0 = *(const float2*)(p + 0);   // x0 y0
        float2 u1 = *(const float2*)(p + 2);   // z0 x1
        float2 u2 = *(const float2*)(p + 4);   // y1 z1
        float h0 = u0.x * u0.x + u0.y * u0.y + u1.x * u1.x;
        float h1 = u1.y * u1.y + u2.x * u2.x + u2.y * u2.y;
        pt[2 * i + 0] = make_float4(u0.x, u1.y, u0.y, u2.x);   // xx, yy
        pt[2 * i + 1] = make_float4(u1.x, u2.y, h0, h1);       // zz, hh
    }

    // query constants: -2*q splatted into both packed halves
    v2f m2x[QPT], m2y[QPT], m2z[QPT];
    float mn[QPT];
    #pragma unroll
    for (int j = 0; j < QPT; ++j) {
        const float* q = query + (size_t)(j * BLOCK + tid) * 3;
        float a = -2.0f * q[0], bb = -2.0f * q[1], c = -2.0f * q[2];
        m2x[j].x = a;  m2x[j].y = a;
        m2y[j].x = bb; m2y[j].y = bb;
        m2z[j].x = c;  m2z[j].y = c;
        mn[j] = FLT_MAX;
    }
    __syncthreads();

    // t_pair = hh + xx*(-2qx) + yy*(-2qy) + zz*(-2qz)  -> 3 pk_fma + 1 min3
    for (int pr = 0; pr < pairs; pr += 2) {
        float4 A0 = pt[2 * pr + 0];          // x0x1 y0y1
        float4 B0 = pt[2 * pr + 1];          // z0z1 h0h1
        float4 A1 = pt[2 * pr + 2];
        float4 B1 = pt[2 * pr + 3];
        v2f xx0 = {A0.x, A0.y}, yy0 = {A0.z, A0.w}, zz0 = {B0.x, B0.y}, hh0 = {B0.z, B0.w};
        v2f xx1 = {A1.x, A1.y}, yy1 = {A1.z, A1.w}, zz1 = {B1.x, B1.y}, hh1 = {B1.z, B1.w};
        #pragma unroll
        for (int j = 0; j < QPT; ++j) {
            v2f t0 = pk_fma(zz0, m2z[j], pk_fma(yy0, m2y[j], pk_fma(xx0, m2x[j], hh0)));
            v2f t1 = pk_fma(zz1, m2z[j], pk_fma(yy1, m2y[j], pk_fma(xx1, m2x[j], hh1)));
            mn[j] = fminf(fminf(mn[j], t0.x), t0.y);
            mn[j] = fminf(fminf(mn[j], t1.x), t1.y);
        }
    }

    float* pp = part + (size_t)(bdir * S + slice) * NPTS;
    #pragma unroll
    for (int j = 0; j < QPT; ++j) pp[j * BLOCK + tid] = mn[j];
}

// ---------------- combine 1: min over slices, add h_q, partial sums ----------
// grid (8, 16): qg covers 512 queries, bdir.  -> ws2[bdir*8 + qg]
__global__ void __launch_bounds__(BLOCK) chamfer_comb1(
    const float* __restrict__ preds,
    const float* __restrict__ gts,
    const float* __restrict__ part,
    float* __restrict__ ws2, int S)
{
    const int qg = blockIdx.x, bdir = blockIdx.y;
    const int b = bdir >> 1, dir = bdir & 1;
    const int tid = threadIdx.x;
    const float* query = ((dir == 0) ? preds : gts) + (size_t)b * NPTS * 3;
    const float* pp = part + (size_t)bdir * S * NPTS;

    float sum = 0.0f;
    #pragma unroll
    for (int r = 0; r < 2; ++r) {
        const int q = qg * 512 + r * BLOCK + tid;
        float m = FLT_MAX;
        for (int s = 0; s < S; ++s) m = fminf(m, pp[(size_t)s * NPTS + q]);
        const float x = query[3 * q], y = query[3 * q + 1], z = query[3 * q + 2];
        sum += m + (x * x + y * y + z * z);
    }

    __shared__ float red[BLOCK];
    red[tid] = sum;
    __syncthreads();
    #pragma unroll
    for (int off = BLOCK / 2; off >= 1; off >>= 1) {
        if (tid < off) red[tid] += red[tid + off];
        __syncthreads();
    }
    if (tid == 0) ws2[bdir * 8 + qg] = red[0];
}

// ---------------- combine 2: out[b] = sum of its 16 group sums --------------
__global__ void chamfer_comb2(const float* __restrict__ ws2, float* __restrict__ out)
{
    const int b = threadIdx.x;
    if (b < NB) {
        float s = 0.0f;
        #pragma unroll
        for (int i = 0; i < 16; ++i) s += ws2[b * 16 + i];
        out[b] = s;
    }
}

extern "C" void kernel_launch(void* const* d_in, const int* in_sizes, int n_in,
                              void* d_out, int out_size, void* d_ws, size_t ws_size,
                              hipStream_t stream)
{
    const float* preds = (const float*)d_in[0];
    const float* gts   = (const float*)d_in[1];
    float* out = (float*)d_out;

    int S = 32;
    while (S > 8 && (size_t)(2 * NB) * S * NPTS * 4 + 4096 > ws_size) S >>= 1;

    float* part = (float*)d_ws;
    float* ws2  = part + (size_t)(2 * NB) * S * NPTS;   // 128 floats

    chamfer_main <<<dim3(S, 2 * NB), BLOCK, 0, stream>>>(preds, gts, part, S);
    chamfer_comb1<<<dim3(8, 2 * NB), BLOCK, 0, stream>>>(preds, gts, part, ws2, S);
    chamfer_comb2<<<1, 64, 0, stream>>>(ws2, out);
}

// Round 5
// 30.543 us; speedup vs baseline: 1.4312x; 1.4312x over previous
//
#include <hip/hip_runtime.h>
#include <float.h>

#define NPTS 4096
#define NB   8

typedef __bf16 bf16x8 __attribute__((ext_vector_type(8)));
typedef float  f32x16 __attribute__((ext_vector_type(16)));

__device__ __forceinline__ float min3f(float a, float b, float c) {
    return fminf(fminf(a, b), c);   // clang fuses to v_min3_f32
}

__device__ __forceinline__ void split_bf(float v, __bf16& hi, __bf16& lo) {
    hi = (__bf16)v;
    lo = (__bf16)(v - (float)hi);
}

// ---------------- main: MFMA distance tiles + in-register col-min ------------
// grid (32, 16): blockIdx.x = rowgrp*8 + jgroup, blockIdx.y = bdir = b*2+dir
// dir0: rows=gts, cols=preds (loss_1 per col); dir1 swapped (loss_2).
// Each wave: 256 rows (8 i-blocks of 32) x 512 cols (16 j-tiles of 32).
// Split-bf16 rank-13 expansion: P[i,j] = h_i + h_j - 2 g.p exactly-ish in one
// v_mfma_f32_32x32x16_bf16 per tile.
// K slots (A,B): 0:(xh,uh) 1:(xh,ul) 2:(xl,uh) 3-5: y/v 6-8: z/w
//                9:(hh_i,1) 10:(hl_i,1) 11:(1,hh_j) 12:(1,hl_j) 13-15: 0
__global__ void __launch_bounds__(256) chamfer_mfma(
    const float* __restrict__ preds,
    const float* __restrict__ gts,
    float* __restrict__ part)
{
    __shared__ __align__(16) __bf16 Btab[2][512][8];   // 16 KB

    const int rowgrp = blockIdx.x >> 3;
    const int jgroup = blockIdx.x & 7;
    const int bdir   = blockIdx.y;
    const int b = bdir >> 1, dir = bdir & 1;

    const float* rows = ((dir == 0) ? gts   : preds) + (size_t)b * NPTS * 3;
    const float* cols = ((dir == 0) ? preds : gts)   + (size_t)b * NPTS * 3;

    const int tid  = threadIdx.x;
    const int lane = tid & 63;
    const int w    = tid >> 6;
    const __bf16 one = (__bf16)1.0f, zero = (__bf16)0.0f;

    // stage B table: 512 cols, split-bf16 of (-2x,-2y,-2z) and h
    #pragma unroll
    for (int r = 0; r < 2; ++r) {
        const int c = tid + r * 256;
        const float* p = cols + (size_t)(jgroup * 512 + c) * 3;
        const float x = p[0], y = p[1], z = p[2];
        const float h = x * x + y * y + z * z;
        __bf16 uh, ul, vh, vl, wh, wl, hh, hl;
        split_bf(-2.0f * x, uh, ul);
        split_bf(-2.0f * y, vh, vl);
        split_bf(-2.0f * z, wh, wl);
        split_bf(h, hh, hl);
        bf16x8 b0, b1;
        b0[0] = uh; b0[1] = ul; b0[2] = uh; b0[3] = vh;
        b0[4] = vl; b0[5] = vh; b0[6] = wh; b0[7] = wl;
        b1[0] = wh; b1[1] = one; b1[2] = one; b1[3] = hh;
        b1[4] = hl; b1[5] = zero; b1[6] = zero; b1[7] = zero;
        *(bf16x8*)&Btab[0][c][0] = b0;
        *(bf16x8*)&Btab[1][c][0] = b1;
    }

    // A fragments: 8 i-blocks x 32 rows; lane half selects k0-7 / k8-15 slots
    bf16x8 afr[8];
    const int rbase = rowgrp * 1024 + w * 256;
    #pragma unroll
    for (int ib = 0; ib < 8; ++ib) {
        const float* g = rows + (size_t)(rbase + ib * 32 + (lane & 31)) * 3;
        const float x = g[0], y = g[1], z = g[2];
        const float h = x * x + y * y + z * z;
        __bf16 xh, xl, yh, yl, zh, zl, hh, hl;
        split_bf(x, xh, xl);
        split_bf(y, yh, yl);
        split_bf(z, zh, zl);
        split_bf(h, hh, hl);
        bf16x8 a;
        if (lane < 32) {
            a[0] = xh; a[1] = xh; a[2] = xl; a[3] = yh;
            a[4] = yh; a[5] = yl; a[6] = zh; a[7] = zh;
        } else {
            a[0] = zl; a[1] = hh; a[2] = hl; a[3] = one;
            a[4] = one; a[5] = zero; a[6] = zero; a[7] = zero;
        }
        afr[ib] = a;
    }
    __syncthreads();

    f32x16 zc = 0.0f;    // C = 0 (everything folded into K)

    float* wsout = part + (size_t)(bdir * 16 + rowgrp * 4 + w) * NPTS
                        + jgroup * 512;

    for (int jt = 0; jt < 16; ++jt) {
        const bf16x8 bfr = *(const bf16x8*)&Btab[lane >> 5][jt * 32 + (lane & 31)][0];
        float pmin = FLT_MAX;
        #pragma unroll
        for (int ib = 0; ib < 8; ++ib) {
            f32x16 d = __builtin_amdgcn_mfma_f32_32x32x16_bf16(afr[ib], bfr, zc, 0, 0, 0);
            const float m0 = min3f(d[0],  d[1],  d[2]);
            const float m1 = min3f(d[3],  d[4],  d[5]);
            const float m2 = min3f(d[6],  d[7],  d[8]);
            const float m3 = min3f(d[9],  d[10], d[11]);
            const float m4 = min3f(d[12], d[13], d[14]);
            const float mm = min3f(min3f(m0, m1, m2), fminf(m3, m4), d[15]);
            pmin = fminf(pmin, mm);
        }
        // combine the two lane-half row-groups -> full 256-row min per col
        pmin = fminf(pmin, __shfl_xor(pmin, 32, 64));
        if (lane < 32) wsout[jt * 32 + (lane & 31)] = pmin;
    }
}

// ---------------- combine: min over 16 row-bands, sum cols -------------------
// grid 32: blockIdx.x = bdir*2 + half; each block sums 2048 cols
__global__ void __launch_bounds__(256) chamfer_comb(
    const float* __restrict__ part, float* __restrict__ ws2)
{
    const int blk  = blockIdx.x;
    const int bdir = blk >> 1, half = blk & 1;
    const int tid  = threadIdx.x;
    const float* p0 = part + (size_t)bdir * 16 * NPTS;

    float sum = 0.0f;
    for (int k = 0; k < 8; ++k) {
        const int col = half * 2048 + k * 256 + tid;
        float m = FLT_MAX;
        #pragma unroll
        for (int wg = 0; wg < 16; ++wg)
            m = fminf(m, p0[(size_t)wg * NPTS + col]);
        sum += m;
    }

    __shared__ float red[256];
    red[tid] = sum;
    __syncthreads();
    #pragma unroll
    for (int off = 128; off >= 1; off >>= 1) {
        if (tid < off) red[tid] += red[tid + off];
        __syncthreads();
    }
    if (tid == 0) ws2[blk] = red[0];
}

// ---------------- final: out[b] = sum of its 4 partial sums ------------------
__global__ void chamfer_final(const float* __restrict__ ws2, float* __restrict__ out)
{
    const int b = threadIdx.x;
    if (b < NB)
        out[b] = (ws2[4 * b] + ws2[4 * b + 1]) + (ws2[4 * b + 2] + ws2[4 * b + 3]);
}

extern "C" void kernel_launch(void* const* d_in, const int* in_sizes, int n_in,
                              void* d_out, int out_size, void* d_ws, size_t ws_size,
                              hipStream_t stream)
{
    const float* preds = (const float*)d_in[0];
    const float* gts   = (const float*)d_in[1];
    float* out  = (float*)d_out;
    float* part = (float*)d_ws;                       // 16*16*4096 f32 = 4 MB
    float* ws2  = part + (size_t)16 * 16 * NPTS;      // 32 f32

    chamfer_mfma <<<dim3(32, 16), 256, 0, stream>>>(preds, gts, part);
    chamfer_comb <<<32, 256, 0, stream>>>(part, ws2);
    chamfer_final<<<1, 64, 0, stream>>>(ws2, out);
}

// Round 6
// 24.316 us; speedup vs baseline: 1.7977x; 1.2561x over previous
//
#include <hip/hip_runtime.h>
#include <float.h>

#define NPTS 4096
#define NB   8

typedef __bf16 bf16x8 __attribute__((ext_vector_type(8)));
typedef float  f32x16 __attribute__((ext_vector_type(16)));

__device__ __forceinline__ float min3f(float a, float b, float c) {
    return fminf(fminf(a, b), c);   // clang fuses to v_min3_f32
}

__device__ __forceinline__ void split_bf(float v, __bf16& hi, __bf16& lo) {
    hi = (__bf16)v;
    lo = (__bf16)(v - (float)hi);
}

// ---------------- main: MFMA distance tiles + in-register col-min ------------
// grid (64, 16): blockIdx.x = rowgrp*8 + jgroup (rowgrp 0..7, jgroup 0..7),
// blockIdx.y = bdir = b*2+dir. dir0: rows=gts, cols=preds; dir1 swapped.
// Block: 512 rows (4 waves x 128) x 512 cols. Split-bf16 rank-13 K-expansion,
// one v_mfma_f32_32x32x16_bf16 per 32x32 tile (layout identical to round 5).
__global__ void __launch_bounds__(256, 4) chamfer_mfma(
    const float* __restrict__ preds,
    const float* __restrict__ gts,
    float* __restrict__ part)
{
    __shared__ __align__(16) __bf16 Btab[2][512][8];   // 16 KB
    __shared__ float pmLds[4][512];                    // 8 KB

    const int rowgrp = blockIdx.x >> 3;
    const int jgroup = blockIdx.x & 7;
    const int bdir   = blockIdx.y;
    const int b = bdir >> 1, dir = bdir & 1;

    const float* rows = ((dir == 0) ? gts   : preds) + (size_t)b * NPTS * 3;
    const float* cols = ((dir == 0) ? preds : gts)   + (size_t)b * NPTS * 3;

    const int tid  = threadIdx.x;
    const int lane = tid & 63;
    const int w    = tid >> 6;
    const __bf16 one = (__bf16)1.0f, zero = (__bf16)0.0f;

    // stage B table: 512 cols, split-bf16 of (-2x,-2y,-2z) and h
    #pragma unroll
    for (int r = 0; r < 2; ++r) {
        const int c = tid + r * 256;
        const float* p = cols + (size_t)(jgroup * 512 + c) * 3;
        const float x = p[0], y = p[1], z = p[2];
        const float h = x * x + y * y + z * z;
        __bf16 uh, ul, vh, vl, wh, wl, hh, hl;
        split_bf(-2.0f * x, uh, ul);
        split_bf(-2.0f * y, vh, vl);
        split_bf(-2.0f * z, wh, wl);
        split_bf(h, hh, hl);
        bf16x8 b0, b1;
        b0[0] = uh; b0[1] = ul; b0[2] = uh; b0[3] = vh;
        b0[4] = vl; b0[5] = vh; b0[6] = wh; b0[7] = wl;
        b1[0] = wh; b1[1] = one; b1[2] = one; b1[3] = hh;
        b1[4] = hl; b1[5] = zero; b1[6] = zero; b1[7] = zero;
        *(bf16x8*)&Btab[0][c][0] = b0;
        *(bf16x8*)&Btab[1][c][0] = b1;
    }

    // A fragments: 4 i-blocks x 32 rows; lane half selects k0-7 / k8-15 slots
    bf16x8 afr[4];
    const int rbase = rowgrp * 512 + w * 128;
    #pragma unroll
    for (int ib = 0; ib < 4; ++ib) {
        const float* g = rows + (size_t)(rbase + ib * 32 + (lane & 31)) * 3;
        const float x = g[0], y = g[1], z = g[2];
        const float h = x * x + y * y + z * z;
        __bf16 xh, xl, yh, yl, zh, zl, hh, hl;
        split_bf(x, xh, xl);
        split_bf(y, yh, yl);
        split_bf(z, zh, zl);
        split_bf(h, hh, hl);
        bf16x8 a;
        if (lane < 32) {
            a[0] = xh; a[1] = xh; a[2] = xl; a[3] = yh;
            a[4] = yh; a[5] = yl; a[6] = zh; a[7] = zh;
        } else {
            a[0] = zl; a[1] = hh; a[2] = hl; a[3] = one;
            a[4] = one; a[5] = zero; a[6] = zero; a[7] = zero;
        }
        afr[ib] = a;
    }
    __syncthreads();

    f32x16 zc = 0.0f;    // C = 0 (everything folded into K)

    for (int jt = 0; jt < 16; ++jt) {
        const bf16x8 bfr = *(const bf16x8*)&Btab[lane >> 5][jt * 32 + (lane & 31)][0];
        float pmin = FLT_MAX;
        #pragma unroll
        for (int ib = 0; ib < 4; ++ib) {
            f32x16 d = __builtin_amdgcn_mfma_f32_32x32x16_bf16(afr[ib], bfr, zc, 0, 0, 0);
            const float m0 = min3f(d[0],  d[1],  d[2]);
            const float m1 = min3f(d[3],  d[4],  d[5]);
            const float m2 = min3f(d[6],  d[7],  d[8]);
            const float m3 = min3f(d[9],  d[10], d[11]);
            const float m4 = min3f(d[12], d[13], d[14]);
            const float mm = min3f(min3f(m0, m1, m2), fminf(m3, m4), d[15]);
            pmin = fminf(pmin, mm);
        }
        // combine the two lane-half row-groups -> 128-row min per col
        pmin = fminf(pmin, __shfl_xor(pmin, 32, 64));
        if (lane < 32) pmLds[w][jt * 32 + (lane & 31)] = pmin;
    }
    __syncthreads();

    // cross-wave (4 row-bands of 128) min -> 512-row band min, write part
    float* wsout = part + (size_t)(bdir * 8 + rowgrp) * NPTS + jgroup * 512;
    #pragma unroll
    for (int r = 0; r < 2; ++r) {
        const int idx = tid + r * 256;
        const float m = fminf(min3f(pmLds[0][idx], pmLds[1][idx], pmLds[2][idx]),
                              pmLds[3][idx]);
        wsout[idx] = m;
    }
}

// ---------------- combine: min over 8 bands, sum cols, atomic into out -------
// grid 64: blk = bdir*4 + quarter; each block sums 1024 cols
__global__ void __launch_bounds__(256) chamfer_comb(
    const float* __restrict__ part, float* __restrict__ out)
{
    const int blk  = blockIdx.x;
    const int bdir = blk >> 2, quarter = blk & 3;
    const int tid  = threadIdx.x;
    const float* p0 = part + (size_t)bdir * 8 * NPTS;

    float sum = 0.0f;
    #pragma unroll
    for (int c = 0; c < 4; ++c) {
        const int col = quarter * 1024 + c * 256 + tid;
        float m = FLT_MAX;
        #pragma unroll
        for (int band = 0; band < 8; ++band)
            m = fminf(m, p0[(size_t)band * NPTS + col]);
        sum += m;
    }

    __shared__ float red[256];
    red[tid] = sum;
    __syncthreads();
    #pragma unroll
    for (int off = 128; off >= 1; off >>= 1) {
        if (tid < off) red[tid] += red[tid + off];
        __syncthreads();
    }
    if (tid == 0) atomicAdd(&out[bdir >> 1], red[0]);
}

extern "C" void kernel_launch(void* const* d_in, const int* in_sizes, int n_in,
                              void* d_out, int out_size, void* d_ws, size_t ws_size,
                              hipStream_t stream)
{
    const float* preds = (const float*)d_in[0];
    const float* gts   = (const float*)d_in[1];
    float* out  = (float*)d_out;
    float* part = (float*)d_ws;                       // 16*8*4096 f32 = 2 MB

    hipMemsetAsync(d_out, 0, NB * sizeof(float), stream);
    chamfer_mfma<<<dim3(64, 16), 256, 0, stream>>>(preds, gts, part);
    chamfer_comb<<<64, 256, 0, stream>>>(part, out);
}